// Round 1
// 2269.539 us; speedup vs baseline: 6.1266x; 6.1266x over previous
//
#include <hip/hip_runtime.h>

#define NN 100000
#define EE 600000
#define RR 1000

typedef unsigned short u16;

__device__ __forceinline__ float bf2f(u16 u) {
    union { unsigned int i; float f; } c; c.i = ((unsigned int)u) << 16; return c.f;
}
__device__ __forceinline__ u16 f2bf(float f) {
    union { float f; unsigned int i; } c; c.f = f;
    unsigned int x = c.i;
    return (u16)((x + 0x7FFFu + ((x >> 16) & 1u)) >> 16);
}
// dtype-adaptive input load (flag decided at runtime by mode 9)
__device__ __forceinline__ float ldin(const void* p, long long i, int f32) {
    if (f32) return ((const float*)p)[i];
    return bf2f(((const u16*)p)[i]);
}
__device__ __forceinline__ void stout(void* p, long long i, float v, int f32) {
    if (f32) ((float*)p)[i] = v;
    else     ((u16*)p)[i] = f2bf(v);
}

// One kernel, mode-dispatched.
//  9: detect input dtype (fp32 vs bf16) -> flagp[0]
//  0: zero gsum; xb = bf16(ent[node_ids])
// CSR build (once; graph constant across layers; lives in old denom region):
//   denom ints: [0,NN)=offs  [NN,2NN)=cnt/cursor  [2NN,2NN+EE)=packed(src|rl<<17)
//  10: zero cnt
//  11: histogram cnt[dst]++
//  12: exclusive scan cnt -> offs (and cursor), single block
//  13: scatter packed edges by dst (atomic cursor)
// Per layer:
//  1: erel = rel @ We[l] + be[l]                       [1000,128] fp32
//  2: q/k/v (bf16) + skip (fp32 -> accum seed); 8-row LDS tile
//  4: FUSED attention per dst node (no atomics): one 128-thread block per node
//     walks CSR edges, shfl-reduce dots per head, single-pass softmax
//     (no max-subtraction; logits O(10)), + layernorm + relu + residual.
//     Writes xb (bf16) and accum (fp32 copy of x).
// Epilogue:
//  5: out = accum (fp32 x), dtype-adaptive
//  7: per channel: gsum partial sums from accum
//  8: out tail = gsum/NN
__global__ void GraphTransformerEncoder_35021163331783_kernel(
    int mode, int layer,
    const int* node_ids, const int* edge_index, const int* edge_type,
    const void* ent, const void* rel,
    const void* Wq, const void* bq, const void* Wk, const void* bk,
    const void* Wv, const void* bv, const void* We, const void* be,
    const void* Ws, const void* bs, const void* lng, const void* lnb,
    void* out,
    float* accum, float* erel, float* denom, float* gsum, float* flagp,
    u16* xb, u16* kb, u16* vb, u16* qb)
{
    __shared__ float xs[1024];
    __shared__ float red[128];
    __shared__ int scnt;
    int tid = blockIdx.x * blockDim.x + threadIdx.x;

    if (mode == 9) {
        if (threadIdx.x == 0) scnt = 0;
        __syncthreads();
        int bad = 0;
        for (int i = threadIdx.x; i < 8192; i += 256) {
            float v = bf2f(((const u16*)ent)[i]);
            if (!(fabsf(v) <= 1000.0f)) bad++;   // catches huge and NaN
        }
        atomicAdd(&scnt, bad);
        __syncthreads();
        if (threadIdx.x == 0) flagp[0] = (scnt > 64) ? 1.0f : 0.0f;
    } else if (mode == 0) {
        if (tid < 128) gsum[tid] = 0.0f;
        if (tid < NN * 128) {
            int isf32 = (flagp[0] != 0.0f);
            int n = tid >> 7, c = tid & 127;
            xb[tid] = f2bf(ldin(ent, (long long)node_ids[n] * 128 + c, isf32));
        }
    } else if (mode == 10) {
        if (tid < NN) ((int*)denom)[NN + tid] = 0;
    } else if (mode == 11) {
        if (tid < EE) {
            int dst = edge_index[EE + tid];
            atomicAdd(&((int*)denom)[NN + dst], 1);
        }
    } else if (mode == 12) {
        // single block, 1024 threads: exclusive scan of cnt -> offs and cursor
        int* offs = (int*)denom;
        int* cnt  = offs + NN;
        int* wsum = (int*)red;            // 17 ints
        int lane = threadIdx.x & 63, wid = threadIdx.x >> 6;
        int base = 0;
        for (int chunk = 0; chunk < NN; chunk += 1024) {
            int i = chunk + (int)threadIdx.x;
            int v = (i < NN) ? cnt[i] : 0;
            int incl = v;
            #pragma unroll
            for (int s = 1; s < 64; s <<= 1) {
                int t = __shfl_up(incl, s, 64);
                if (lane >= s) incl += t;
            }
            if (lane == 63) wsum[wid] = incl;
            __syncthreads();
            if (threadIdx.x == 0) {
                int run = 0;
                for (int w = 0; w < 16; ++w) { int t = wsum[w]; wsum[w] = run; run += t; }
                wsum[16] = run;
            }
            __syncthreads();
            int excl = base + wsum[wid] + incl - v;
            if (i < NN) { offs[i] = excl; cnt[i] = excl; }  // cnt becomes cursor
            base += wsum[16];
            __syncthreads();   // protect wsum before next chunk overwrites
        }
    } else if (mode == 13) {
        if (tid < EE) {
            int src = edge_index[tid];
            int dst = edge_index[EE + tid];
            int rl  = edge_type[tid];
            int* cur = (int*)denom + NN;
            int pos = atomicAdd(&cur[dst], 1);
            ((unsigned int*)denom)[2 * NN + pos] =
                (unsigned int)src | ((unsigned int)rl << 17);
        }
    } else if (mode == 1) {
        if (tid < RR * 128) {
            int isf32 = (flagp[0] != 0.0f);
            int r = tid >> 7, d = tid & 127;
            float acc = 0.0f;
            for (int k = 0; k < 128; ++k)
                acc += ldin(rel, r * 128 + k, isf32)
                     * ldin(We, (long long)layer * 16384 + k * 128 + d, isf32);
            erel[tid] = acc + ldin(be, layer * 128 + d, isf32);
        }
    } else if (mode == 2) {
        // block: 128 threads; mat = blockIdx.x & 3; 8 node-rows staged in LDS
        int d = threadIdx.x;
        int mat = blockIdx.x & 3;
        int n0 = (blockIdx.x >> 2) * 8;
        #pragma unroll
        for (int i = 0; i < 8; ++i)
            xs[i * 128 + d] = bf2f(xb[(long long)(n0 + i) * 128 + d]);
        __syncthreads();
        const void* W; const void* bias;
        if (mat == 0) { W = Wq; bias = bq; }
        else if (mat == 1) { W = Wk; bias = bk; }
        else if (mat == 2) { W = Wv; bias = bv; }
        else { W = Ws; bias = bs; }
        int isf32 = (flagp[0] != 0.0f);
        float acc[8];
        #pragma unroll
        for (int i = 0; i < 8; ++i) acc[i] = 0.0f;
        for (int k = 0; k < 128; ++k) {
            float wv = ldin(W, (long long)layer * 16384 + k * 128 + d, isf32);
            #pragma unroll
            for (int i = 0; i < 8; ++i)
                acc[i] += xs[i * 128 + k] * wv;
        }
        float bc = ldin(bias, layer * 128 + d, isf32);
        #pragma unroll
        for (int i = 0; i < 8; ++i) {
            long long o = (long long)(n0 + i) * 128 + d;
            float v = acc[i] + bc;
            if (mat == 0) qb[o] = f2bf(v);
            else if (mat == 1) kb[o] = f2bf(v);
            else if (mat == 2) vb[o] = f2bf(v);
            else accum[o] = v;
        }
    } else if (mode == 4) {
        // fused attention + LN + relu + residual; one block per dst node
        long long n = blockIdx.x;
        int c = threadIdx.x;                 // 0..127, head = c>>4
        int isf32 = (flagp[0] != 0.0f);
        const int* offs = (const int*)denom;
        const unsigned int* packed = (const unsigned int*)denom + 2 * NN;
        float qc = bf2f(qb[n * 128 + c]);
        float seed = accum[n * 128 + c];     // skip (x @ Ws + bs)
        int beg = offs[n];
        int end = (n == NN - 1) ? EE : offs[n + 1];
        float macc = 0.0f, dsum = 0.0f;
        for (int idx = beg; idx < end; ++idx) {
            unsigned int pk = packed[idx];
            int src = (int)(pk & 0x1FFFFu);
            int rl  = (int)(pk >> 17);
            float ec = erel[rl * 128 + c];
            float kc = bf2f(kb[(long long)src * 128 + c]);
            float vc = bf2f(vb[(long long)src * 128 + c]);
            float t = qc * (kc + ec);
            #pragma unroll
            for (int m = 1; m < 16; m <<= 1) t += __shfl_xor(t, m, 16);
            // softmax max-subtraction dropped: mathematically identical;
            // logits here are O(10) so expf cannot overflow
            float w = __expf(t * 0.25f);
            dsum += w;
            macc += w * (vc + ec);
        }
        float o = seed + macc / (dsum + 1e-16f);
        // layernorm + relu + residual
        red[c] = o;
        __syncthreads();
        for (int s = 64; s > 0; s >>= 1) {
            if (c < s) red[c] += red[c + s];
            __syncthreads();
        }
        float mean = red[0] * 0.0078125f;
        __syncthreads();
        float d = o - mean;
        red[c] = d * d;
        __syncthreads();
        for (int s = 64; s > 0; s >>= 1) {
            if (c < s) red[c] += red[c + s];
            __syncthreads();
        }
        float var = red[0] * 0.0078125f;
        float rs = rsqrtf(var + 1e-5f);
        float y = d * rs * ldin(lng, layer * 128 + c, isf32)
                + ldin(lnb, layer * 128 + c, isf32);
        if (y < 0.0f) y = 0.0f;
        float xv = bf2f(xb[n * 128 + c]) + y;
        xb[n * 128 + c] = f2bf(xv);
        accum[n * 128 + c] = xv;   // fp32 x; seed already consumed. out copied
                                   // later (can't write out here: qb aliases it)
    } else if (mode == 5) {
        if (tid < NN * 128) {
            int isf32 = (flagp[0] != 0.0f);
            stout(out, tid, accum[tid], isf32);
        }
    } else if (mode == 7) {
        int c = threadIdx.x;
        float acc = 0.0f;
        for (long long n = blockIdx.x; n < NN; n += gridDim.x)
            acc += accum[n * 128 + c];
        atomicAdd(&gsum[c], acc);
    } else if (mode == 8) {
        if (tid < 128) {
            int isf32 = (flagp[0] != 0.0f);
            stout(out, (long long)NN * 128 + tid, gsum[tid] * (1.0f / (float)NN), isf32);
        }
    }
}

#define GTE_ARGS node_ids, edge_index, edge_type, ent, rel, Wq, bq, Wk, bk, \
    Wv, bv, We, be, Ws, bs, lng, lnb, out, accum, erel, denom, gsum, flagp, \
    xb, kb, vb, qb

extern "C" void kernel_launch(void* const* d_in, const int* in_sizes, int n_in,
                              void* d_out, int out_size, void* d_ws, size_t ws_size,
                              hipStream_t stream) {
    (void)in_sizes; (void)n_in; (void)out_size; (void)ws_size;

    const int* node_ids   = (const int*)d_in[0];
    const int* edge_index = (const int*)d_in[1];
    const int* edge_type  = (const int*)d_in[2];
    const void* ent = d_in[3];
    const void* rel = d_in[4];
    const void* Wq  = d_in[5];
    const void* bq  = d_in[6];
    const void* Wk  = d_in[7];
    const void* bk  = d_in[8];
    const void* Wv  = d_in[9];
    const void* bv  = d_in[10];
    const void* We  = d_in[11];
    const void* be  = d_in[12];
    const void* Ws  = d_in[13];
    const void* bs  = d_in[14];
    const void* lng = d_in[15];
    const void* lnb = d_in[16];
    void* out = d_out;

    // Compact workspace: ~126 MiB. qb lives in d_out's dead space (out is only
    // written by modes 5/8, after qb's last use in layer-2 mode 4).
    // denom region (800000 f32) is repurposed as CSR:
    //   ints [0,NN)=offs, [NN,2NN)=cnt/cursor, [2NN,2NN+EE)=packed — 800000 exact.
    float* accum = (float*)d_ws;            // 12.8M f32
    float* erel  = accum + 12800000;        // 128K f32
    float* denom = erel  + 128000;          // 800K f32 (CSR)
    float* gsum  = denom + 800000;          // 128 f32
    float* flagp = gsum  + 128;             // 1 f32 (+pad)
    u16* xb = (u16*)(flagp + 64);           // 12.8M bf16
    u16* kb = xb + 12800000;                // 12.8M bf16
    u16* vb = kb + 12800000;                // 12.8M bf16
    u16* qb = (u16*)d_out;                  // 12.8M bf16 (scratch in d_out)

    GraphTransformerEncoder_35021163331783_kernel<<<1, 256, 0, stream>>>(9, 0, GTE_ARGS);
    GraphTransformerEncoder_35021163331783_kernel<<<50000, 256, 0, stream>>>(0, 0, GTE_ARGS);
    // CSR build (once; graph constant across layers)
    GraphTransformerEncoder_35021163331783_kernel<<<391, 256, 0, stream>>>(10, 0, GTE_ARGS);
    GraphTransformerEncoder_35021163331783_kernel<<<2344, 256, 0, stream>>>(11, 0, GTE_ARGS);
    GraphTransformerEncoder_35021163331783_kernel<<<1, 1024, 0, stream>>>(12, 0, GTE_ARGS);
    GraphTransformerEncoder_35021163331783_kernel<<<2344, 256, 0, stream>>>(13, 0, GTE_ARGS);
    for (int l = 0; l < 3; ++l) {
        GraphTransformerEncoder_35021163331783_kernel<<<500, 256, 0, stream>>>(1, l, GTE_ARGS);
        GraphTransformerEncoder_35021163331783_kernel<<<50000, 128, 0, stream>>>(2, l, GTE_ARGS);
        GraphTransformerEncoder_35021163331783_kernel<<<NN, 128, 0, stream>>>(4, l, GTE_ARGS);
    }
    GraphTransformerEncoder_35021163331783_kernel<<<50000, 256, 0, stream>>>(5, 0, GTE_ARGS);
    GraphTransformerEncoder_35021163331783_kernel<<<512, 128, 0, stream>>>(7, 0, GTE_ARGS);
    GraphTransformerEncoder_35021163331783_kernel<<<1, 128, 0, stream>>>(8, 0, GTE_ARGS);
}

// Round 2
// 1916.952 us; speedup vs baseline: 7.2534x; 1.1839x over previous
//
#include <hip/hip_runtime.h>

#define NN 100000
#define EE 600000
#define RR 1000

typedef unsigned short u16;
typedef __attribute__((ext_vector_type(8))) short short8;
typedef __attribute__((ext_vector_type(4))) float f32x4;

__device__ __forceinline__ float bf2f(u16 u) {
    union { unsigned int i; float f; } c; c.i = ((unsigned int)u) << 16; return c.f;
}
__device__ __forceinline__ u16 f2bf(float f) {
    union { float f; unsigned int i; } c; c.f = f;
    unsigned int x = c.i;
    return (u16)((x + 0x7FFFu + ((x >> 16) & 1u)) >> 16);
}
// dtype-adaptive input load (flag decided at runtime by mode 9)
__device__ __forceinline__ float ldin(const void* p, long long i, int f32) {
    if (f32) return ((const float*)p)[i];
    return bf2f(((const u16*)p)[i]);
}
__device__ __forceinline__ void stout(void* p, long long i, float v, int f32) {
    if (f32) ((float*)p)[i] = v;
    else     ((u16*)p)[i] = f2bf(v);
}

// One kernel, mode-dispatched.
//  9: detect input dtype (fp32 vs bf16) -> flagp[0]
//  0: zero gsum; xb = bf16(ent[node_ids])
// CSR build (once; graph constant across layers; lives in old denom region):
//   denom ints: [0,NN)=offs  [NN,2NN)=cnt/cursor  [2NN,2NN+EE)=packed(src|rl<<17)
//  10: zero cnt
//  11: histogram cnt[dst]++
//  12: exclusive scan cnt -> offs (and cursor), single block
//  13: scatter packed edges by dst (atomic cursor)
// Per layer:
//  1: erel = rel @ We[l] + be[l]                       [1000,128] fp32
// 14: pack W{q,k,v,s}[l] into MFMA B-fragment order (bf16) -> wbf
//  2: MFMA q/k/v (bf16) + skip (fp32 -> accum seed); 32-row tile, 4 waves,
//     wave w computes mat w via mfma_f32_16x16x32_bf16 (2 Mt x 8 Nt x 4 Ks)
//  4: FUSED attention per dst node (no atomics): one 128-thread block per node
//     walks CSR edges, shfl-reduce dots per head, single-pass softmax
//     (no max-subtraction; logits O(10)), + layernorm + relu + residual.
//     Writes xb (bf16) and accum (fp32 copy of x).
// Epilogue:
//  5: out = accum (fp32 x), dtype-adaptive
//  7: per channel: gsum partial sums from accum
//  8: out tail = gsum/NN
__global__ void GraphTransformerEncoder_35021163331783_kernel(
    int mode, int layer,
    const int* node_ids, const int* edge_index, const int* edge_type,
    const void* ent, const void* rel,
    const void* Wq, const void* bq, const void* Wk, const void* bk,
    const void* Wv, const void* bv, const void* We, const void* be,
    const void* Ws, const void* bs, const void* lng, const void* lnb,
    void* out,
    float* accum, float* erel, float* denom, float* gsum, float* flagp,
    u16* xb, u16* kb, u16* vb, u16* qb, u16* wbf)
{
    __shared__ float red[128];
    __shared__ __align__(16) u16 xt[32 * 128];   // 8 KiB x-tile (mode 2)
    __shared__ int scnt;
    int tid = blockIdx.x * blockDim.x + threadIdx.x;

    if (mode == 9) {
        if (threadIdx.x == 0) scnt = 0;
        __syncthreads();
        int bad = 0;
        for (int i = threadIdx.x; i < 8192; i += 256) {
            float v = bf2f(((const u16*)ent)[i]);
            if (!(fabsf(v) <= 1000.0f)) bad++;   // catches huge and NaN
        }
        atomicAdd(&scnt, bad);
        __syncthreads();
        if (threadIdx.x == 0) flagp[0] = (scnt > 64) ? 1.0f : 0.0f;
    } else if (mode == 0) {
        if (tid < 128) gsum[tid] = 0.0f;
        if (tid < NN * 128) {
            int isf32 = (flagp[0] != 0.0f);
            int n = tid >> 7, c = tid & 127;
            xb[tid] = f2bf(ldin(ent, (long long)node_ids[n] * 128 + c, isf32));
        }
    } else if (mode == 10) {
        if (tid < NN) ((int*)denom)[NN + tid] = 0;
    } else if (mode == 11) {
        if (tid < EE) {
            int dst = edge_index[EE + tid];
            atomicAdd(&((int*)denom)[NN + dst], 1);
        }
    } else if (mode == 12) {
        // single block, 1024 threads: exclusive scan of cnt -> offs and cursor
        int* offs = (int*)denom;
        int* cnt  = offs + NN;
        int* wsum = (int*)red;            // 17 ints
        int lane = threadIdx.x & 63, wid = threadIdx.x >> 6;
        int base = 0;
        for (int chunk = 0; chunk < NN; chunk += 1024) {
            int i = chunk + (int)threadIdx.x;
            int v = (i < NN) ? cnt[i] : 0;
            int incl = v;
            #pragma unroll
            for (int s = 1; s < 64; s <<= 1) {
                int t = __shfl_up(incl, s, 64);
                if (lane >= s) incl += t;
            }
            if (lane == 63) wsum[wid] = incl;
            __syncthreads();
            if (threadIdx.x == 0) {
                int run = 0;
                for (int w = 0; w < 16; ++w) { int t = wsum[w]; wsum[w] = run; run += t; }
                wsum[16] = run;
            }
            __syncthreads();
            int excl = base + wsum[wid] + incl - v;
            if (i < NN) { offs[i] = excl; cnt[i] = excl; }  // cnt becomes cursor
            base += wsum[16];
            __syncthreads();   // protect wsum before next chunk overwrites
        }
    } else if (mode == 13) {
        if (tid < EE) {
            int src = edge_index[tid];
            int dst = edge_index[EE + tid];
            int rl  = edge_type[tid];
            int* cur = (int*)denom + NN;
            int pos = atomicAdd(&cur[dst], 1);
            ((unsigned int*)denom)[2 * NN + pos] =
                (unsigned int)src | ((unsigned int)rl << 17);
        }
    } else if (mode == 1) {
        if (tid < RR * 128) {
            int isf32 = (flagp[0] != 0.0f);
            int r = tid >> 7, d = tid & 127;
            float acc = 0.0f;
            for (int k = 0; k < 128; ++k)
                acc += ldin(rel, r * 128 + k, isf32)
                     * ldin(We, (long long)layer * 16384 + k * 128 + d, isf32);
            erel[tid] = acc + ldin(be, layer * 128 + d, isf32);
        }
    } else if (mode == 14) {
        // pack weights into B-fragment-linear bf16: wbf[mat][nt][ks][lane][j]
        // element = W[k = ks*32 + (lane>>4)*8 + j][d = nt*16 + (lane&15)]
        if (tid < 4 * 16384) {
            int isf32 = (flagp[0] != 0.0f);
            int mat = tid >> 14;
            int rem = tid & 16383;
            int nt = rem >> 11;
            int ks = (rem >> 9) & 3;
            int l  = (rem >> 3) & 63;
            int j  = rem & 7;
            int k = ks * 32 + ((l >> 4) << 3) + j;
            int d = nt * 16 + (l & 15);
            const void* W = (mat == 0) ? Wq : (mat == 1) ? Wk : (mat == 2) ? Wv : Ws;
            wbf[tid] = f2bf(ldin(W, (long long)layer * 16384 + k * 128 + d, isf32));
        }
    } else if (mode == 2) {
        // MFMA projection: 32-row tile per block, 256 threads = 4 waves.
        // Wave w computes out = x_tile @ W[w]  (w: 0=q 1=k 2=v 3=skip)
        int n0 = blockIdx.x * 32;
        int t = threadIdx.x;
        // stage x tile into LDS; XOR-swizzle 16B units so ds_read_b128 at
        // row-stride 256B is conflict-free (unit ^= row&7)
        for (int u = t; u < 512; u += 256) {
            int row = u >> 4, un = u & 15;
            uint4 d4 = *(const uint4*)(xb + (long long)(n0 + row) * 128 + un * 8);
            *(uint4*)(xt + row * 128 + ((un ^ (row & 7)) << 3)) = d4;
        }
        __syncthreads();
        int wv = t >> 6;           // mat index
        int l  = t & 63;
        int lr = l & 15, lg = l >> 4;
        const u16* wf = wbf + (long long)wv * 16384;   // [nt][ks][lane][8]
        f32x4 acc[2][8];
        #pragma unroll
        for (int mt = 0; mt < 2; ++mt)
            #pragma unroll
            for (int nt = 0; nt < 8; ++nt) acc[mt][nt] = (f32x4)0.0f;
        #pragma unroll
        for (int ks = 0; ks < 4; ++ks) {
            int un = ks * 4 + lg;
            int r0 = lr, r1 = 16 + lr;
            short8 a0 = *(const short8*)(xt + r0 * 128 + ((un ^ (r0 & 7)) << 3));
            short8 a1 = *(const short8*)(xt + r1 * 128 + ((un ^ (r1 & 7)) << 3));
            short8 b[8];
            #pragma unroll
            for (int nt = 0; nt < 8; ++nt)
                b[nt] = *(const short8*)(wf + (((nt * 4 + ks) * 64 + l) << 3));
            #pragma unroll
            for (int nt = 0; nt < 8; ++nt) {
                acc[0][nt] = __builtin_amdgcn_mfma_f32_16x16x32_bf16(a0, b[nt], acc[0][nt], 0, 0, 0);
                acc[1][nt] = __builtin_amdgcn_mfma_f32_16x16x32_bf16(a1, b[nt], acc[1][nt], 0, 0, 0);
            }
        }
        int isf32 = (flagp[0] != 0.0f);
        const void* bias = (wv == 0) ? bq : (wv == 1) ? bk : (wv == 2) ? bv : bs;
        #pragma unroll
        for (int nt = 0; nt < 8; ++nt) {
            int col = nt * 16 + lr;
            float bc = ldin(bias, layer * 128 + col, isf32);
            #pragma unroll
            for (int mt = 0; mt < 2; ++mt) {
                #pragma unroll
                for (int v = 0; v < 4; ++v) {
                    int row = n0 + mt * 16 + lg * 4 + v;   // D: row=(l>>4)*4+reg
                    long long o = (long long)row * 128 + col;
                    float val = acc[mt][nt][v] + bc;
                    if (wv == 0) qb[o] = f2bf(val);
                    else if (wv == 1) kb[o] = f2bf(val);
                    else if (wv == 2) vb[o] = f2bf(val);
                    else accum[o] = val;
                }
            }
        }
    } else if (mode == 4) {
        // fused attention + LN + relu + residual; one block per dst node
        long long n = blockIdx.x;
        int c = threadIdx.x;                 // 0..127, head = c>>4
        int isf32 = (flagp[0] != 0.0f);
        const int* offs = (const int*)denom;
        const unsigned int* packed = (const unsigned int*)denom + 2 * NN;
        float qc = bf2f(qb[n * 128 + c]);
        float seed = accum[n * 128 + c];     // skip (x @ Ws + bs)
        int beg = offs[n];
        int end = (n == NN - 1) ? EE : offs[n + 1];
        float macc = 0.0f, dsum = 0.0f;
        for (int idx = beg; idx < end; ++idx) {
            unsigned int pk = packed[idx];
            int src = (int)(pk & 0x1FFFFu);
            int rl  = (int)(pk >> 17);
            float ec = erel[rl * 128 + c];
            float kc = bf2f(kb[(long long)src * 128 + c]);
            float vc = bf2f(vb[(long long)src * 128 + c]);
            float t = qc * (kc + ec);
            #pragma unroll
            for (int m = 1; m < 16; m <<= 1) t += __shfl_xor(t, m, 16);
            // softmax max-subtraction dropped: mathematically identical;
            // logits here are O(10) so expf cannot overflow
            float w = __expf(t * 0.25f);
            dsum += w;
            macc += w * (vc + ec);
        }
        float o = seed + macc / (dsum + 1e-16f);
        // layernorm + relu + residual
        red[c] = o;
        __syncthreads();
        for (int s = 64; s > 0; s >>= 1) {
            if (c < s) red[c] += red[c + s];
            __syncthreads();
        }
        float mean = red[0] * 0.0078125f;
        __syncthreads();
        float d = o - mean;
        red[c] = d * d;
        __syncthreads();
        for (int s = 64; s > 0; s >>= 1) {
            if (c < s) red[c] += red[c + s];
            __syncthreads();
        }
        float var = red[0] * 0.0078125f;
        float rs = rsqrtf(var + 1e-5f);
        float y = d * rs * ldin(lng, layer * 128 + c, isf32)
                + ldin(lnb, layer * 128 + c, isf32);
        if (y < 0.0f) y = 0.0f;
        float xv = bf2f(xb[n * 128 + c]) + y;
        xb[n * 128 + c] = f2bf(xv);
        accum[n * 128 + c] = xv;   // fp32 x; seed already consumed. out copied
                                   // later (can't write out here: qb aliases it)
    } else if (mode == 5) {
        if (tid < NN * 128) {
            int isf32 = (flagp[0] != 0.0f);
            stout(out, tid, accum[tid], isf32);
        }
    } else if (mode == 7) {
        int c = threadIdx.x;
        float acc = 0.0f;
        for (long long n = blockIdx.x; n < NN; n += gridDim.x)
            acc += accum[n * 128 + c];
        atomicAdd(&gsum[c], acc);
    } else if (mode == 8) {
        if (tid < 128) {
            int isf32 = (flagp[0] != 0.0f);
            stout(out, (long long)NN * 128 + tid, gsum[tid] * (1.0f / (float)NN), isf32);
        }
    }
}

#define GTE_ARGS node_ids, edge_index, edge_type, ent, rel, Wq, bq, Wk, bk, \
    Wv, bv, We, be, Ws, bs, lng, lnb, out, accum, erel, denom, gsum, flagp, \
    xb, kb, vb, qb, wbf

extern "C" void kernel_launch(void* const* d_in, const int* in_sizes, int n_in,
                              void* d_out, int out_size, void* d_ws, size_t ws_size,
                              hipStream_t stream) {
    (void)in_sizes; (void)n_in; (void)out_size; (void)ws_size;

    const int* node_ids   = (const int*)d_in[0];
    const int* edge_index = (const int*)d_in[1];
    const int* edge_type  = (const int*)d_in[2];
    const void* ent = d_in[3];
    const void* rel = d_in[4];
    const void* Wq  = d_in[5];
    const void* bq  = d_in[6];
    const void* Wk  = d_in[7];
    const void* bk  = d_in[8];
    const void* Wv  = d_in[9];
    const void* bv  = d_in[10];
    const void* We  = d_in[11];
    const void* be  = d_in[12];
    const void* Ws  = d_in[13];
    const void* bs  = d_in[14];
    const void* lng = d_in[15];
    const void* lnb = d_in[16];
    void* out = d_out;

    // Compact workspace: ~126 MiB (+128 KiB wbf). qb lives in d_out's dead
    // space (out only written by modes 5/8, after qb's last use in l=2 mode 4).
    // denom region (800000 f32) repurposed as CSR:
    //   ints [0,NN)=offs, [NN,2NN)=cnt/cursor, [2NN,2NN+EE)=packed — 800000.
    float* accum = (float*)d_ws;            // 12.8M f32
    float* erel  = accum + 12800000;        // 128K f32
    float* denom = erel  + 128000;          // 800K f32 (CSR)
    float* gsum  = denom + 800000;          // 128 f32
    float* flagp = gsum  + 128;             // 1 f32 (+pad)
    u16* xb = (u16*)(flagp + 64);           // 12.8M bf16
    u16* kb = xb + 12800000;                // 12.8M bf16
    u16* vb = kb + 12800000;                // 12.8M bf16
    u16* wbf = vb + 12800000;               // 64K bf16 (fragment-packed weights)
    u16* qb = (u16*)d_out;                  // 12.8M bf16 (scratch in d_out)

    GraphTransformerEncoder_35021163331783_kernel<<<1, 256, 0, stream>>>(9, 0, GTE_ARGS);
    GraphTransformerEncoder_35021163331783_kernel<<<50000, 256, 0, stream>>>(0, 0, GTE_ARGS);
    // CSR build (once; graph constant across layers)
    GraphTransformerEncoder_35021163331783_kernel<<<391, 256, 0, stream>>>(10, 0, GTE_ARGS);
    GraphTransformerEncoder_35021163331783_kernel<<<2344, 256, 0, stream>>>(11, 0, GTE_ARGS);
    GraphTransformerEncoder_35021163331783_kernel<<<1, 1024, 0, stream>>>(12, 0, GTE_ARGS);
    GraphTransformerEncoder_35021163331783_kernel<<<2344, 256, 0, stream>>>(13, 0, GTE_ARGS);
    for (int l = 0; l < 3; ++l) {
        GraphTransformerEncoder_35021163331783_kernel<<<500, 256, 0, stream>>>(1, l, GTE_ARGS);
        GraphTransformerEncoder_35021163331783_kernel<<<256, 256, 0, stream>>>(14, l, GTE_ARGS);
        GraphTransformerEncoder_35021163331783_kernel<<<3125, 256, 0, stream>>>(2, l, GTE_ARGS);
        GraphTransformerEncoder_35021163331783_kernel<<<NN, 128, 0, stream>>>(4, l, GTE_ARGS);
    }
    GraphTransformerEncoder_35021163331783_kernel<<<50000, 256, 0, stream>>>(5, 0, GTE_ARGS);
    GraphTransformerEncoder_35021163331783_kernel<<<512, 128, 0, stream>>>(7, 0, GTE_ARGS);
    GraphTransformerEncoder_35021163331783_kernel<<<1, 128, 0, stream>>>(8, 0, GTE_ARGS);
}

// Round 3
// 1389.460 us; speedup vs baseline: 10.0071x; 1.3796x over previous
//
#include <hip/hip_runtime.h>

#define NN 100000
#define EE 600000
#define RR 1000

typedef unsigned short u16;
typedef __attribute__((ext_vector_type(8))) short short8;
typedef __attribute__((ext_vector_type(4))) float f32x4;

__device__ __forceinline__ float bf2f(u16 u) {
    union { unsigned int i; float f; } c; c.i = ((unsigned int)u) << 16; return c.f;
}
__device__ __forceinline__ u16 f2bf(float f) {
    union { float f; unsigned int i; } c; c.f = f;
    unsigned int x = c.i;
    return (u16)((x + 0x7FFFu + ((x >> 16) & 1u)) >> 16);
}
__device__ __forceinline__ unsigned int pack2bf(float a, float b) {
    return (unsigned int)f2bf(a) | ((unsigned int)f2bf(b) << 16);
}
// dtype-adaptive input load (flag decided at runtime by mode 9)
__device__ __forceinline__ float ldin(const void* p, long long i, int f32) {
    if (f32) return ((const float*)p)[i];
    return bf2f(((const u16*)p)[i]);
}
__device__ __forceinline__ void stout(void* p, long long i, float v, int f32) {
    if (f32) ((float*)p)[i] = v;
    else     ((u16*)p)[i] = f2bf(v);
}

// One kernel, mode-dispatched.
//  9: detect input dtype (fp32 vs bf16) -> flagp[0]
//  0: zero gsum; xb = bf16(ent[node_ids])
// CSR build (once; graph constant across layers; lives in old denom region):
//   denom ints: [0,NN)=offs  [NN,2NN)=cnt/cursor  [2NN,2NN+EE)=packed(src|rl<<17)
//  10: zero cnt   11: histogram cnt[dst]++   12: exclusive scan (single block)
//  13: scatter packed edges by dst (atomic cursor)
// Per layer:
//  1: erel = rel @ We[l] + be[l]                       [1000,128] fp32
// 14: pack W{q,k,v,s}[l] into MFMA B-fragment order (bf16) -> wbf
//  2: MFMA q/k/v (bf16) + skip (fp32 -> accum seed); 32-row tile, 4 waves
//  4: FUSED attention per dst node: one 64-lane WAVE per node (4 nodes/block),
//     2 channels per lane, edges processed in chunks of 4 with all gathers
//     issued before compute (latency amortization). Single-pass softmax (no
//     max-subtraction; logits O(10)). Wave-shuffle LayerNorm (no LDS/barriers)
//     + relu + residual. Writes xb (bf16) and accum (fp32 copy of x).
// Epilogue:
//  5: out = accum (fp32 x), dtype-adaptive
//  7: per channel: gsum partial sums from accum
//  8: out tail = gsum/NN
__global__ void GraphTransformerEncoder_35021163331783_kernel(
    int mode, int layer,
    const int* node_ids, const int* edge_index, const int* edge_type,
    const void* ent, const void* rel,
    const void* Wq, const void* bq, const void* Wk, const void* bk,
    const void* Wv, const void* bv, const void* We, const void* be,
    const void* Ws, const void* bs, const void* lng, const void* lnb,
    void* out,
    float* accum, float* erel, float* denom, float* gsum, float* flagp,
    u16* xb, u16* kb, u16* vb, u16* qb, u16* wbf)
{
    __shared__ float red[128];
    __shared__ __align__(16) u16 xt[32 * 128];   // 8 KiB x-tile (mode 2)
    __shared__ int scnt;
    int tid = blockIdx.x * blockDim.x + threadIdx.x;

    if (mode == 9) {
        if (threadIdx.x == 0) scnt = 0;
        __syncthreads();
        int bad = 0;
        for (int i = threadIdx.x; i < 8192; i += 256) {
            float v = bf2f(((const u16*)ent)[i]);
            if (!(fabsf(v) <= 1000.0f)) bad++;   // catches huge and NaN
        }
        atomicAdd(&scnt, bad);
        __syncthreads();
        if (threadIdx.x == 0) flagp[0] = (scnt > 64) ? 1.0f : 0.0f;
    } else if (mode == 0) {
        if (tid < 128) gsum[tid] = 0.0f;
        if (tid < NN * 128) {
            int isf32 = (flagp[0] != 0.0f);
            int n = tid >> 7, c = tid & 127;
            xb[tid] = f2bf(ldin(ent, (long long)node_ids[n] * 128 + c, isf32));
        }
    } else if (mode == 10) {
        if (tid < NN) ((int*)denom)[NN + tid] = 0;
    } else if (mode == 11) {
        if (tid < EE) {
            int dst = edge_index[EE + tid];
            atomicAdd(&((int*)denom)[NN + dst], 1);
        }
    } else if (mode == 12) {
        // single block, 1024 threads: exclusive scan of cnt -> offs and cursor
        int* offs = (int*)denom;
        int* cnt  = offs + NN;
        int* wsum = (int*)red;            // 17 ints
        int lane = threadIdx.x & 63, wid = threadIdx.x >> 6;
        int base = 0;
        for (int chunk = 0; chunk < NN; chunk += 1024) {
            int i = chunk + (int)threadIdx.x;
            int v = (i < NN) ? cnt[i] : 0;
            int incl = v;
            #pragma unroll
            for (int s = 1; s < 64; s <<= 1) {
                int t = __shfl_up(incl, s, 64);
                if (lane >= s) incl += t;
            }
            if (lane == 63) wsum[wid] = incl;
            __syncthreads();
            if (threadIdx.x == 0) {
                int run = 0;
                for (int w = 0; w < 16; ++w) { int t = wsum[w]; wsum[w] = run; run += t; }
                wsum[16] = run;
            }
            __syncthreads();
            int excl = base + wsum[wid] + incl - v;
            if (i < NN) { offs[i] = excl; cnt[i] = excl; }  // cnt becomes cursor
            base += wsum[16];
            __syncthreads();   // protect wsum before next chunk overwrites
        }
    } else if (mode == 13) {
        if (tid < EE) {
            int src = edge_index[tid];
            int dst = edge_index[EE + tid];
            int rl  = edge_type[tid];
            int* cur = (int*)denom + NN;
            int pos = atomicAdd(&cur[dst], 1);
            ((unsigned int*)denom)[2 * NN + pos] =
                (unsigned int)src | ((unsigned int)rl << 17);
        }
    } else if (mode == 1) {
        if (tid < RR * 128) {
            int isf32 = (flagp[0] != 0.0f);
            int r = tid >> 7, d = tid & 127;
            float acc = 0.0f;
            for (int k = 0; k < 128; ++k)
                acc += ldin(rel, r * 128 + k, isf32)
                     * ldin(We, (long long)layer * 16384 + k * 128 + d, isf32);
            erel[tid] = acc + ldin(be, layer * 128 + d, isf32);
        }
    } else if (mode == 14) {
        // pack weights into B-fragment-linear bf16: wbf[mat][nt][ks][lane][j]
        // element = W[k = ks*32 + (lane>>4)*8 + j][d = nt*16 + (lane&15)]
        if (tid < 4 * 16384) {
            int isf32 = (flagp[0] != 0.0f);
            int mat = tid >> 14;
            int rem = tid & 16383;
            int nt = rem >> 11;
            int ks = (rem >> 9) & 3;
            int l  = (rem >> 3) & 63;
            int j  = rem & 7;
            int k = ks * 32 + ((l >> 4) << 3) + j;
            int d = nt * 16 + (l & 15);
            const void* W = (mat == 0) ? Wq : (mat == 1) ? Wk : (mat == 2) ? Wv : Ws;
            wbf[tid] = f2bf(ldin(W, (long long)layer * 16384 + k * 128 + d, isf32));
        }
    } else if (mode == 2) {
        // MFMA projection: 32-row tile per block, 256 threads = 4 waves.
        // Wave w computes out = x_tile @ W[w]  (w: 0=q 1=k 2=v 3=skip)
        int n0 = blockIdx.x * 32;
        int t = threadIdx.x;
        // stage x tile into LDS; XOR-swizzle 16B units so ds_read_b128 at
        // row-stride 256B is conflict-free (unit ^= row&7)
        for (int u = t; u < 512; u += 256) {
            int row = u >> 4, un = u & 15;
            uint4 d4 = *(const uint4*)(xb + (long long)(n0 + row) * 128 + un * 8);
            *(uint4*)(xt + row * 128 + ((un ^ (row & 7)) << 3)) = d4;
        }
        __syncthreads();
        int wv = t >> 6;           // mat index
        int l  = t & 63;
        int lr = l & 15, lg = l >> 4;
        const u16* wf = wbf + (long long)wv * 16384;   // [nt][ks][lane][8]
        f32x4 acc[2][8];
        #pragma unroll
        for (int mt = 0; mt < 2; ++mt)
            #pragma unroll
            for (int nt = 0; nt < 8; ++nt) acc[mt][nt] = (f32x4)0.0f;
        #pragma unroll
        for (int ks = 0; ks < 4; ++ks) {
            int un = ks * 4 + lg;
            int r0 = lr, r1 = 16 + lr;
            short8 a0 = *(const short8*)(xt + r0 * 128 + ((un ^ (r0 & 7)) << 3));
            short8 a1 = *(const short8*)(xt + r1 * 128 + ((un ^ (r1 & 7)) << 3));
            short8 b[8];
            #pragma unroll
            for (int nt = 0; nt < 8; ++nt)
                b[nt] = *(const short8*)(wf + (((nt * 4 + ks) * 64 + l) << 3));
            #pragma unroll
            for (int nt = 0; nt < 8; ++nt) {
                acc[0][nt] = __builtin_amdgcn_mfma_f32_16x16x32_bf16(a0, b[nt], acc[0][nt], 0, 0, 0);
                acc[1][nt] = __builtin_amdgcn_mfma_f32_16x16x32_bf16(a1, b[nt], acc[1][nt], 0, 0, 0);
            }
        }
        int isf32 = (flagp[0] != 0.0f);
        const void* bias = (wv == 0) ? bq : (wv == 1) ? bk : (wv == 2) ? bv : bs;
        #pragma unroll
        for (int nt = 0; nt < 8; ++nt) {
            int col = nt * 16 + lr;
            float bc = ldin(bias, layer * 128 + col, isf32);
            #pragma unroll
            for (int mt = 0; mt < 2; ++mt) {
                #pragma unroll
                for (int v = 0; v < 4; ++v) {
                    int row = n0 + mt * 16 + lg * 4 + v;   // D: row=(l>>4)*4+reg
                    long long o = (long long)row * 128 + col;
                    float val = acc[mt][nt][v] + bc;
                    if (wv == 0) qb[o] = f2bf(val);
                    else if (wv == 1) kb[o] = f2bf(val);
                    else if (wv == 2) vb[o] = f2bf(val);
                    else accum[o] = val;
                }
            }
        }
    } else if (mode == 4) {
        // fused attention + LN + relu + residual; one 64-lane wave per node,
        // 4 nodes per 256-thread block; 2 channels per lane; no LDS/barriers.
        long long n = (long long)blockIdx.x * 4 + (threadIdx.x >> 6);
        if (n < NN) {
            int l = threadIdx.x & 63;            // lane; head = l>>3
            int isf32 = (flagp[0] != 0.0f);
            const int* offs = (const int*)denom;
            const unsigned int* packed = (const unsigned int*)denom + 2 * NN;
            unsigned int qu = ((const unsigned int*)(qb + n * 128))[l];
            float q0 = bf2f((u16)(qu & 0xFFFFu)), q1 = bf2f((u16)(qu >> 16));
            float2 seed = ((const float2*)(accum + n * 128))[l];
            int beg = offs[n];
            int end = (n == NN - 1) ? EE : offs[n + 1];
            float m0 = 0.0f, m1 = 0.0f, dsum = 0.0f;
            for (int base = beg; base < end; base += 4) {
                int cnt = end - base;             // wave-uniform
                unsigned int ku[4], vu[4];
                float2 ef[4];
                #pragma unroll
                for (int j = 0; j < 4; ++j) {
                    if (j < cnt) {
                        unsigned int pk = packed[base + j];
                        long long src = (long long)(pk & 0x1FFFFu);
                        int rl = (int)(pk >> 17);
                        ku[j] = ((const unsigned int*)(kb + src * 128))[l];
                        vu[j] = ((const unsigned int*)(vb + src * 128))[l];
                        ef[j] = ((const float2*)(erel + rl * 128))[l];
                    }
                }
                #pragma unroll
                for (int j = 0; j < 4; ++j) {
                    if (j < cnt) {
                        float e0 = ef[j].x, e1 = ef[j].y;
                        float t = q0 * (bf2f((u16)(ku[j] & 0xFFFFu)) + e0)
                                + q1 * (bf2f((u16)(ku[j] >> 16)) + e1);
                        t += __shfl_xor(t, 1, 8);
                        t += __shfl_xor(t, 2, 8);
                        t += __shfl_xor(t, 4, 8);
                        // softmax max-subtraction dropped: identical math;
                        // logits O(10) so expf cannot overflow
                        float w = __expf(t * 0.25f);
                        dsum += w;
                        m0 += w * (bf2f((u16)(vu[j] & 0xFFFFu)) + e0);
                        m1 += w * (bf2f((u16)(vu[j] >> 16)) + e1);
                    }
                }
            }
            float inv = 1.0f / (dsum + 1e-16f);
            float o0 = seed.x + m0 * inv;
            float o1 = seed.y + m1 * inv;
            // wave-shuffle layernorm over 128 channels (2 per lane)
            float s = o0 + o1;
            #pragma unroll
            for (int m = 1; m < 64; m <<= 1) s += __shfl_xor(s, m, 64);
            float mean = s * 0.0078125f;
            float d0 = o0 - mean, d1 = o1 - mean;
            float vs = d0 * d0 + d1 * d1;
            #pragma unroll
            for (int m = 1; m < 64; m <<= 1) vs += __shfl_xor(vs, m, 64);
            float rs = rsqrtf(vs * 0.0078125f + 1e-5f);
            float y0 = d0 * rs * ldin(lng, layer * 128 + 2 * l, isf32)
                     + ldin(lnb, layer * 128 + 2 * l, isf32);
            float y1 = d1 * rs * ldin(lng, layer * 128 + 2 * l + 1, isf32)
                     + ldin(lnb, layer * 128 + 2 * l + 1, isf32);
            if (y0 < 0.0f) y0 = 0.0f;
            if (y1 < 0.0f) y1 = 0.0f;
            unsigned int xu = ((const unsigned int*)(xb + n * 128))[l];
            float xv0 = bf2f((u16)(xu & 0xFFFFu)) + y0;
            float xv1 = bf2f((u16)(xu >> 16)) + y1;
            ((unsigned int*)(xb + n * 128))[l] = pack2bf(xv0, xv1);
            ((float2*)(accum + n * 128))[l] = make_float2(xv0, xv1);
            // fp32 x; seed already consumed. out copied later (qb aliases out)
        }
    } else if (mode == 5) {
        if (tid < NN * 128) {
            int isf32 = (flagp[0] != 0.0f);
            stout(out, tid, accum[tid], isf32);
        }
    } else if (mode == 7) {
        int c = threadIdx.x;
        float acc = 0.0f;
        for (long long n = blockIdx.x; n < NN; n += gridDim.x)
            acc += accum[n * 128 + c];
        atomicAdd(&gsum[c], acc);
    } else if (mode == 8) {
        if (tid < 128) {
            int isf32 = (flagp[0] != 0.0f);
            stout(out, (long long)NN * 128 + tid, gsum[tid] * (1.0f / (float)NN), isf32);
        }
    }
}

#define GTE_ARGS node_ids, edge_index, edge_type, ent, rel, Wq, bq, Wk, bk, \
    Wv, bv, We, be, Ws, bs, lng, lnb, out, accum, erel, denom, gsum, flagp, \
    xb, kb, vb, qb, wbf

extern "C" void kernel_launch(void* const* d_in, const int* in_sizes, int n_in,
                              void* d_out, int out_size, void* d_ws, size_t ws_size,
                              hipStream_t stream) {
    (void)in_sizes; (void)n_in; (void)out_size; (void)ws_size;

    const int* node_ids   = (const int*)d_in[0];
    const int* edge_index = (const int*)d_in[1];
    const int* edge_type  = (const int*)d_in[2];
    const void* ent = d_in[3];
    const void* rel = d_in[4];
    const void* Wq  = d_in[5];
    const void* bq  = d_in[6];
    const void* Wk  = d_in[7];
    const void* bk  = d_in[8];
    const void* Wv  = d_in[9];
    const void* bv  = d_in[10];
    const void* We  = d_in[11];
    const void* be  = d_in[12];
    const void* Ws  = d_in[13];
    const void* bs  = d_in[14];
    const void* lng = d_in[15];
    const void* lnb = d_in[16];
    void* out = d_out;

    // Compact workspace: ~126 MiB (+128 KiB wbf). qb lives in d_out's dead
    // space (out only written by modes 5/8, after qb's last use in l=2 mode 4).
    // denom region (800000 f32) repurposed as CSR:
    //   ints [0,NN)=offs, [NN,2NN)=cnt/cursor, [2NN,2NN+EE)=packed — 800000.
    float* accum = (float*)d_ws;            // 12.8M f32
    float* erel  = accum + 12800000;        // 128K f32
    float* denom = erel  + 128000;          // 800K f32 (CSR)
    float* gsum  = denom + 800000;          // 128 f32
    float* flagp = gsum  + 128;             // 1 f32 (+pad)
    u16* xb = (u16*)(flagp + 64);           // 12.8M bf16
    u16* kb = xb + 12800000;                // 12.8M bf16
    u16* vb = kb + 12800000;                // 12.8M bf16
    u16* wbf = vb + 12800000;               // 64K bf16 (fragment-packed weights)
    u16* qb = (u16*)d_out;                  // 12.8M bf16 (scratch in d_out)

    GraphTransformerEncoder_35021163331783_kernel<<<1, 256, 0, stream>>>(9, 0, GTE_ARGS);
    GraphTransformerEncoder_35021163331783_kernel<<<50000, 256, 0, stream>>>(0, 0, GTE_ARGS);
    // CSR build (once; graph constant across layers)
    GraphTransformerEncoder_35021163331783_kernel<<<391, 256, 0, stream>>>(10, 0, GTE_ARGS);
    GraphTransformerEncoder_35021163331783_kernel<<<2344, 256, 0, stream>>>(11, 0, GTE_ARGS);
    GraphTransformerEncoder_35021163331783_kernel<<<1, 1024, 0, stream>>>(12, 0, GTE_ARGS);
    GraphTransformerEncoder_35021163331783_kernel<<<2344, 256, 0, stream>>>(13, 0, GTE_ARGS);
    for (int l = 0; l < 3; ++l) {
        GraphTransformerEncoder_35021163331783_kernel<<<500, 256, 0, stream>>>(1, l, GTE_ARGS);
        GraphTransformerEncoder_35021163331783_kernel<<<256, 256, 0, stream>>>(14, l, GTE_ARGS);
        GraphTransformerEncoder_35021163331783_kernel<<<3125, 256, 0, stream>>>(2, l, GTE_ARGS);
        GraphTransformerEncoder_35021163331783_kernel<<<25000, 256, 0, stream>>>(4, l, GTE_ARGS);
    }
    GraphTransformerEncoder_35021163331783_kernel<<<50000, 256, 0, stream>>>(5, 0, GTE_ARGS);
    GraphTransformerEncoder_35021163331783_kernel<<<512, 128, 0, stream>>>(7, 0, GTE_ARGS);
    GraphTransformerEncoder_35021163331783_kernel<<<1, 128, 0, stream>>>(8, 0, GTE_ARGS);
}

// Round 4
// 1336.450 us; speedup vs baseline: 10.4040x; 1.0397x over previous
//
#include <hip/hip_runtime.h>

#define NN 100000
#define EE 600000
#define RR 1000

typedef unsigned short u16;
typedef __attribute__((ext_vector_type(8))) short short8;
typedef __attribute__((ext_vector_type(4))) float f32x4;

__device__ __forceinline__ float bf2f(u16 u) {
    union { unsigned int i; float f; } c; c.i = ((unsigned int)u) << 16; return c.f;
}
__device__ __forceinline__ u16 f2bf(float f) {
    union { float f; unsigned int i; } c; c.f = f;
    unsigned int x = c.i;
    return (u16)((x + 0x7FFFu + ((x >> 16) & 1u)) >> 16);
}
__device__ __forceinline__ unsigned int pack2bf(float a, float b) {
    return (unsigned int)f2bf(a) | ((unsigned int)f2bf(b) << 16);
}
// dtype-adaptive input load (flag decided at runtime by mode 9)
__device__ __forceinline__ float ldin(const void* p, long long i, int f32) {
    if (f32) return ((const float*)p)[i];
    return bf2f(((const u16*)p)[i]);
}
__device__ __forceinline__ void stout(void* p, long long i, float v, int f32) {
    if (f32) ((float*)p)[i] = v;
    else     ((u16*)p)[i] = f2bf(v);
}

// One kernel, mode-dispatched.
//  9: detect input dtype (fp32 vs bf16) -> flagp[0]
//  0: zero gsum; xb = bf16(ent[node_ids])
// CSR build (once; graph constant across layers; lives in old denom region):
//   denom ints: [0,NN)=offs  [NN,2NN)=cnt/cursor  [2NN,2NN+EE)=packed(src|rl<<17)
//  10: zero cnt   11: histogram cnt[dst]++   12: exclusive scan (single block)
//  13: scatter packed edges by dst (atomic cursor)
// Per layer:
//  1: erel = rel @ We[l] + be[l]                       [1000,128] fp32
// 14: pack W{q,k,v,s}[l] into MFMA B-fragment order (bf16) -> wbf
//  2: MFMA q/k/v (bf16) + skip (fp32 -> accum seed); 32-row tile, 4 waves.
//     k and v are written INTERLEAVED into kvb: row n (512B) holds, per lane l,
//     u32 pair [k(2l),k(2l+1)] [v(2l),v(2l+1)] -> mode 4 gets k+v in ONE uint2.
//  4: FUSED attention per dst node: one 64-lane WAVE per node (4 nodes/block),
//     2 channels per lane, edges in chunks of 8 with ALL gathers issued before
//     compute (1 uint2 kv gather + 1 float2 erel gather per edge). Single-pass
//     softmax (no max-subtraction; logits O(10)). Wave-shuffle LayerNorm +
//     relu + residual. Writes xb (bf16); fp32 x copy to accum ONLY in layer 2.
// Epilogue:
//  5: out = accum (fp32 x), dtype-adaptive; fused per-channel gsum partials
//  8: out tail = gsum/NN
__global__ void GraphTransformerEncoder_35021163331783_kernel(
    int mode, int layer,
    const int* node_ids, const int* edge_index, const int* edge_type,
    const void* ent, const void* rel,
    const void* Wq, const void* bq, const void* Wk, const void* bk,
    const void* Wv, const void* bv, const void* We, const void* be,
    const void* Ws, const void* bs, const void* lng, const void* lnb,
    void* out,
    float* accum, float* erel, float* denom, float* gsum, float* flagp,
    u16* xb, u16* kvb, u16* qb, u16* wbf)
{
    __shared__ float red[128];
    __shared__ __align__(16) u16 xt[32 * 128];   // 8 KiB x-tile (mode 2)
    __shared__ int scnt;
    int tid = blockIdx.x * blockDim.x + threadIdx.x;

    if (mode == 9) {
        if (threadIdx.x == 0) scnt = 0;
        __syncthreads();
        int bad = 0;
        for (int i = threadIdx.x; i < 8192; i += 256) {
            float v = bf2f(((const u16*)ent)[i]);
            if (!(fabsf(v) <= 1000.0f)) bad++;   // catches huge and NaN
        }
        atomicAdd(&scnt, bad);
        __syncthreads();
        if (threadIdx.x == 0) flagp[0] = (scnt > 64) ? 1.0f : 0.0f;
    } else if (mode == 0) {
        if (tid < 128) gsum[tid] = 0.0f;
        if (tid < NN * 128) {
            int isf32 = (flagp[0] != 0.0f);
            int n = tid >> 7, c = tid & 127;
            xb[tid] = f2bf(ldin(ent, (long long)node_ids[n] * 128 + c, isf32));
        }
    } else if (mode == 10) {
        if (tid < NN) ((int*)denom)[NN + tid] = 0;
    } else if (mode == 11) {
        if (tid < EE) {
            int dst = edge_index[EE + tid];
            atomicAdd(&((int*)denom)[NN + dst], 1);
        }
    } else if (mode == 12) {
        // single block, 1024 threads: exclusive scan of cnt -> offs and cursor
        int* offs = (int*)denom;
        int* cnt  = offs + NN;
        int* wsum = (int*)red;            // 17 ints
        int lane = threadIdx.x & 63, wid = threadIdx.x >> 6;
        int base = 0;
        for (int chunk = 0; chunk < NN; chunk += 1024) {
            int i = chunk + (int)threadIdx.x;
            int v = (i < NN) ? cnt[i] : 0;
            int incl = v;
            #pragma unroll
            for (int s = 1; s < 64; s <<= 1) {
                int t = __shfl_up(incl, s, 64);
                if (lane >= s) incl += t;
            }
            if (lane == 63) wsum[wid] = incl;
            __syncthreads();
            if (threadIdx.x == 0) {
                int run = 0;
                for (int w = 0; w < 16; ++w) { int t = wsum[w]; wsum[w] = run; run += t; }
                wsum[16] = run;
            }
            __syncthreads();
            int excl = base + wsum[wid] + incl - v;
            if (i < NN) { offs[i] = excl; cnt[i] = excl; }  // cnt becomes cursor
            base += wsum[16];
            __syncthreads();   // protect wsum before next chunk overwrites
        }
    } else if (mode == 13) {
        if (tid < EE) {
            int src = edge_index[tid];
            int dst = edge_index[EE + tid];
            int rl  = edge_type[tid];
            int* cur = (int*)denom + NN;
            int pos = atomicAdd(&cur[dst], 1);
            ((unsigned int*)denom)[2 * NN + pos] =
                (unsigned int)src | ((unsigned int)rl << 17);
        }
    } else if (mode == 1) {
        if (tid < RR * 128) {
            int isf32 = (flagp[0] != 0.0f);
            int r = tid >> 7, d = tid & 127;
            float acc = 0.0f;
            for (int k = 0; k < 128; ++k)
                acc += ldin(rel, r * 128 + k, isf32)
                     * ldin(We, (long long)layer * 16384 + k * 128 + d, isf32);
            erel[tid] = acc + ldin(be, layer * 128 + d, isf32);
        }
    } else if (mode == 14) {
        // pack weights into B-fragment-linear bf16: wbf[mat][nt][ks][lane][j]
        // element = W[k = ks*32 + (lane>>4)*8 + j][d = nt*16 + (lane&15)]
        if (tid < 4 * 16384) {
            int isf32 = (flagp[0] != 0.0f);
            int mat = tid >> 14;
            int rem = tid & 16383;
            int nt = rem >> 11;
            int ks = (rem >> 9) & 3;
            int l  = (rem >> 3) & 63;
            int j  = rem & 7;
            int k = ks * 32 + ((l >> 4) << 3) + j;
            int d = nt * 16 + (l & 15);
            const void* W = (mat == 0) ? Wq : (mat == 1) ? Wk : (mat == 2) ? Wv : Ws;
            wbf[tid] = f2bf(ldin(W, (long long)layer * 16384 + k * 128 + d, isf32));
        }
    } else if (mode == 2) {
        // MFMA projection: 32-row tile per block, 256 threads = 4 waves.
        // Wave w computes out = x_tile @ W[w]  (w: 0=q 1=k 2=v 3=skip)
        int n0 = blockIdx.x * 32;
        int t = threadIdx.x;
        // stage x tile into LDS; XOR-swizzle 16B units so ds_read_b128 at
        // row-stride 256B is conflict-free (unit ^= row&7)
        for (int u = t; u < 512; u += 256) {
            int row = u >> 4, un = u & 15;
            uint4 d4 = *(const uint4*)(xb + (long long)(n0 + row) * 128 + un * 8);
            *(uint4*)(xt + row * 128 + ((un ^ (row & 7)) << 3)) = d4;
        }
        __syncthreads();
        int wv = t >> 6;           // mat index
        int l  = t & 63;
        int lr = l & 15, lg = l >> 4;
        const u16* wf = wbf + (long long)wv * 16384;   // [nt][ks][lane][8]
        f32x4 acc[2][8];
        #pragma unroll
        for (int mt = 0; mt < 2; ++mt)
            #pragma unroll
            for (int nt = 0; nt < 8; ++nt) acc[mt][nt] = (f32x4)0.0f;
        #pragma unroll
        for (int ks = 0; ks < 4; ++ks) {
            int un = ks * 4 + lg;
            int r0 = lr, r1 = 16 + lr;
            short8 a0 = *(const short8*)(xt + r0 * 128 + ((un ^ (r0 & 7)) << 3));
            short8 a1 = *(const short8*)(xt + r1 * 128 + ((un ^ (r1 & 7)) << 3));
            short8 b[8];
            #pragma unroll
            for (int nt = 0; nt < 8; ++nt)
                b[nt] = *(const short8*)(wf + (((nt * 4 + ks) * 64 + l) << 3));
            #pragma unroll
            for (int nt = 0; nt < 8; ++nt) {
                acc[0][nt] = __builtin_amdgcn_mfma_f32_16x16x32_bf16(a0, b[nt], acc[0][nt], 0, 0, 0);
                acc[1][nt] = __builtin_amdgcn_mfma_f32_16x16x32_bf16(a1, b[nt], acc[1][nt], 0, 0, 0);
            }
        }
        int isf32 = (flagp[0] != 0.0f);
        const void* bias = (wv == 0) ? bq : (wv == 1) ? bk : (wv == 2) ? bv : bs;
        #pragma unroll
        for (int nt = 0; nt < 8; ++nt) {
            int col = nt * 16 + lr;
            float bc = ldin(bias, layer * 128 + col, isf32);
            #pragma unroll
            for (int mt = 0; mt < 2; ++mt) {
                #pragma unroll
                for (int v = 0; v < 4; ++v) {
                    int row = n0 + mt * 16 + lg * 4 + v;   // D: row=(l>>4)*4+reg
                    long long o = (long long)row * 128 + col;
                    float val = acc[mt][nt][v] + bc;
                    if (wv == 0) qb[o] = f2bf(val);
                    else if (wv == 1)   // k interleaved: [k2c,k2c+1,v2c,v2c+1]
                        kvb[(long long)row * 256 + ((col >> 1) << 2) + (col & 1)] = f2bf(val);
                    else if (wv == 2)   // v interleaved
                        kvb[(long long)row * 256 + ((col >> 1) << 2) + 2 + (col & 1)] = f2bf(val);
                    else accum[o] = val;
                }
            }
        }
    } else if (mode == 4) {
        // fused attention + LN + relu + residual; one 64-lane wave per node,
        // 4 nodes per 256-thread block; 2 channels per lane; no LDS/barriers.
        // Edges in chunks of 8; per edge ONE uint2 kv gather + ONE float2 erel.
        long long n = (long long)blockIdx.x * 4 + (threadIdx.x >> 6);
        if (n < NN) {
            int l = threadIdx.x & 63;            // lane; head = l>>3
            int isf32 = (flagp[0] != 0.0f);
            const int* offs = (const int*)denom;
            const unsigned int* packed = (const unsigned int*)denom + 2 * NN;
            unsigned int qu = ((const unsigned int*)(qb + n * 128))[l];
            float q0 = bf2f((u16)(qu & 0xFFFFu)), q1 = bf2f((u16)(qu >> 16));
            float2 seed = ((const float2*)(accum + n * 128))[l];
            int beg = offs[n];
            int end = (n == NN - 1) ? EE : offs[n + 1];
            float m0 = 0.0f, m1 = 0.0f, dsum = 0.0f;
            for (int base = beg; base < end; base += 8) {
                int cnt = end - base;             // wave-uniform
                uint2 kv[8];
                float2 ef[8];
                #pragma unroll
                for (int j = 0; j < 8; ++j) {
                    if (j < cnt) {
                        unsigned int pk = packed[base + j];
                        long long src = (long long)(pk & 0x1FFFFu);
                        int rl = (int)(pk >> 17);
                        kv[j] = ((const uint2*)(kvb + src * 256))[l];
                        ef[j] = ((const float2*)(erel + rl * 128))[l];
                    }
                }
                #pragma unroll
                for (int j = 0; j < 8; ++j) {
                    if (j < cnt) {
                        float e0 = ef[j].x, e1 = ef[j].y;
                        float t = q0 * (bf2f((u16)(kv[j].x & 0xFFFFu)) + e0)
                                + q1 * (bf2f((u16)(kv[j].x >> 16)) + e1);
                        t += __shfl_xor(t, 1, 8);
                        t += __shfl_xor(t, 2, 8);
                        t += __shfl_xor(t, 4, 8);
                        // softmax max-subtraction dropped: identical math;
                        // logits O(10) so expf cannot overflow
                        float w = __expf(t * 0.25f);
                        dsum += w;
                        m0 += w * (bf2f((u16)(kv[j].y & 0xFFFFu)) + e0);
                        m1 += w * (bf2f((u16)(kv[j].y >> 16)) + e1);
                    }
                }
            }
            float inv = 1.0f / (dsum + 1e-16f);
            float o0 = seed.x + m0 * inv;
            float o1 = seed.y + m1 * inv;
            // wave-shuffle layernorm over 128 channels (2 per lane)
            float s = o0 + o1;
            #pragma unroll
            for (int m = 1; m < 64; m <<= 1) s += __shfl_xor(s, m, 64);
            float mean = s * 0.0078125f;
            float d0 = o0 - mean, d1 = o1 - mean;
            float vs = d0 * d0 + d1 * d1;
            #pragma unroll
            for (int m = 1; m < 64; m <<= 1) vs += __shfl_xor(vs, m, 64);
            float rs = rsqrtf(vs * 0.0078125f + 1e-5f);
            float y0 = d0 * rs * ldin(lng, layer * 128 + 2 * l, isf32)
                     + ldin(lnb, layer * 128 + 2 * l, isf32);
            float y1 = d1 * rs * ldin(lng, layer * 128 + 2 * l + 1, isf32)
                     + ldin(lnb, layer * 128 + 2 * l + 1, isf32);
            if (y0 < 0.0f) y0 = 0.0f;
            if (y1 < 0.0f) y1 = 0.0f;
            unsigned int xu = ((const unsigned int*)(xb + n * 128))[l];
            float xv0 = bf2f((u16)(xu & 0xFFFFu)) + y0;
            float xv1 = bf2f((u16)(xu >> 16)) + y1;
            ((unsigned int*)(xb + n * 128))[l] = pack2bf(xv0, xv1);
            // fp32 x needed only by the epilogue -> write only in final layer
            // (layers 0/1: accum gets overwritten by next mode 2 anyway)
            if (layer == 2)
                ((float2*)(accum + n * 128))[l] = make_float2(xv0, xv1);
            // out copied later (qb aliases out)
        }
    } else if (mode == 5) {
        // out = accum (fp32 x) + fused per-channel gsum partial sums
        int c = threadIdx.x & 127;
        int half = threadIdx.x >> 7;
        int isf32 = (flagp[0] != 0.0f);
        float acc = 0.0f;
        for (long long n = (long long)blockIdx.x * 2 + half; n < NN;
             n += (long long)gridDim.x * 2) {
            float v = accum[n * 128 + c];
            stout(out, n * 128 + c, v, isf32);
            acc += v;
        }
        if (half) red[c] = acc;
        __syncthreads();
        if (!half) atomicAdd(&gsum[c], acc + red[c]);
    } else if (mode == 8) {
        if (tid < 128) {
            int isf32 = (flagp[0] != 0.0f);
            stout(out, (long long)NN * 128 + tid, gsum[tid] * (1.0f / (float)NN), isf32);
        }
    }
}

#define GTE_ARGS node_ids, edge_index, edge_type, ent, rel, Wq, bq, Wk, bk, \
    Wv, bv, We, be, Ws, bs, lng, lnb, out, accum, erel, denom, gsum, flagp, \
    xb, kvb, qb, wbf

extern "C" void kernel_launch(void* const* d_in, const int* in_sizes, int n_in,
                              void* d_out, int out_size, void* d_ws, size_t ws_size,
                              hipStream_t stream) {
    (void)in_sizes; (void)n_in; (void)out_size; (void)ws_size;

    const int* node_ids   = (const int*)d_in[0];
    const int* edge_index = (const int*)d_in[1];
    const int* edge_type  = (const int*)d_in[2];
    const void* ent = d_in[3];
    const void* rel = d_in[4];
    const void* Wq  = d_in[5];
    const void* bq  = d_in[6];
    const void* Wk  = d_in[7];
    const void* bk  = d_in[8];
    const void* Wv  = d_in[9];
    const void* bv  = d_in[10];
    const void* We  = d_in[11];
    const void* be  = d_in[12];
    const void* Ws  = d_in[13];
    const void* bs  = d_in[14];
    const void* lng = d_in[15];
    const void* lnb = d_in[16];
    void* out = d_out;

    // Compact workspace: ~132 MiB. qb lives in d_out's dead space (out only
    // written by modes 5/8, after qb's last use in l=2 mode 4).
    // denom region (800000 f32) repurposed as CSR:
    //   ints [0,NN)=offs, [NN,2NN)=cnt/cursor, [2NN,2NN+EE)=packed — 800000.
    float* accum = (float*)d_ws;            // 12.8M f32
    float* erel  = accum + 12800000;        // 128K f32
    float* denom = erel  + 128000;          // 800K f32 (CSR)
    float* gsum  = denom + 800000;          // 128 f32
    float* flagp = gsum  + 128;             // 1 f32 (+pad)
    u16* xb  = (u16*)(flagp + 64);          // 12.8M bf16
    u16* kvb = xb + 12800000;               // 25.6M bf16 (k,v interleaved)
    u16* wbf = kvb + 25600000;              // 64K bf16 (fragment-packed weights)
    u16* qb  = (u16*)d_out;                 // 12.8M bf16 (scratch in d_out)

    GraphTransformerEncoder_35021163331783_kernel<<<1, 256, 0, stream>>>(9, 0, GTE_ARGS);
    GraphTransformerEncoder_35021163331783_kernel<<<50000, 256, 0, stream>>>(0, 0, GTE_ARGS);
    // CSR build (once; graph constant across layers)
    GraphTransformerEncoder_35021163331783_kernel<<<391, 256, 0, stream>>>(10, 0, GTE_ARGS);
    GraphTransformerEncoder_35021163331783_kernel<<<2344, 256, 0, stream>>>(11, 0, GTE_ARGS);
    GraphTransformerEncoder_35021163331783_kernel<<<1, 1024, 0, stream>>>(12, 0, GTE_ARGS);
    GraphTransformerEncoder_35021163331783_kernel<<<2344, 256, 0, stream>>>(13, 0, GTE_ARGS);
    for (int l = 0; l < 3; ++l) {
        GraphTransformerEncoder_35021163331783_kernel<<<500, 256, 0, stream>>>(1, l, GTE_ARGS);
        GraphTransformerEncoder_35021163331783_kernel<<<256, 256, 0, stream>>>(14, l, GTE_ARGS);
        GraphTransformerEncoder_35021163331783_kernel<<<3125, 256, 0, stream>>>(2, l, GTE_ARGS);
        GraphTransformerEncoder_35021163331783_kernel<<<25000, 256, 0, stream>>>(4, l, GTE_ARGS);
    }
    GraphTransformerEncoder_35021163331783_kernel<<<512, 256, 0, stream>>>(5, 0, GTE_ARGS);
    GraphTransformerEncoder_35021163331783_kernel<<<1, 128, 0, stream>>>(8, 0, GTE_ARGS);
}